// Round 12
// baseline (172.474 us; speedup 1.0000x reference)
//
#include <hip/hip_runtime.h>
#include <stdint.h>

typedef unsigned short u16;
typedef __attribute__((ext_vector_type(8))) short short8;
typedef __attribute__((ext_vector_type(4))) short short4v;
typedef __attribute__((ext_vector_type(4))) float f32x4;
typedef __attribute__((ext_vector_type(2))) unsigned uint2v;

#define AS1C(p) ((const __attribute__((address_space(1))) void*)(p))
#define AS3(p)  ((__attribute__((address_space(3))) void*)(p))

__device__ __forceinline__ u16 to_bf16(float f) {
  unsigned u = __builtin_bit_cast(unsigned, f);
  u += 0x7FFFu + ((u >> 16) & 1u);
  return (u16)(u >> 16);
}

// ---------------------------------------------------------------------------
// x[b][c][n] fp32 -> xT[b][n][c] bf16. Tile 64c x 32n, short4 stores.
__global__ __launch_bounds__(256) void xpose_cvt(const float* __restrict__ x,
                                                 u16* __restrict__ xT) {
  __shared__ float ls[64][34];
  int b = blockIdx.z;
  int n0 = blockIdx.x * 32, c0 = blockIdx.y * 64;
  int t = threadIdx.x;
  const float* xp = x + (size_t)b * 524288;
  int nn = t & 31, ccb = (t >> 5) * 8;
#pragma unroll
  for (int i = 0; i < 8; ++i)
    ls[ccb + i][nn] = xp[(size_t)(c0 + ccb + i) * 1024 + n0 + nn];
  __syncthreads();
  u16* op = xT + (size_t)b * 524288 + (size_t)n0 * 512 + c0;
  int nn2 = t >> 3, cb = (t & 7) * 4;
#pragma unroll
  for (int pass = 0; pass < 2; ++pass) {
    int c = cb + pass * 32;
    short4v v;
#pragma unroll
    for (int i = 0; i < 4; ++i) v[i] = (short)to_bf16(ls[c + i][nn2]);
    *(short4v*)&op[(size_t)nn2 * 512 + c] = v;
  }
}

// Both weight conversions in one launch: blocks [0,768) -> qkv_w (196608 f4),
// [768,1024) -> out_w (65536 f4). Per-element op identical (bit-identical).
__global__ __launch_bounds__(256) void cvt_both(const float* __restrict__ qw,
                                                const float* __restrict__ ow,
                                                u16* __restrict__ dq,
                                                u16* __restrict__ dw) {
  int blk = blockIdx.x;
  const float* s;
  u16* d;
  int i;
  if (blk < 768) {
    s = qw; d = dq; i = blk * 256 + threadIdx.x;
  } else {
    s = ow; d = dw; i = (blk - 768) * 256 + threadIdx.x;
  }
  f32x4 v = *(const f32x4*)&s[i * 4];
  short4v o;
#pragma unroll
  for (int j = 0; j < 4; ++j) o[j] = (short)to_bf16(v[j]);
  *(short4v*)&d[i * 4] = o;
}

// ---------------------------------------------------------------------------
// Generic 128x128-tile bf16 GEMM, K=512, BK=32 (m97 structure; linear
// K/V output layouts). Unchanged from the passing R10 configuration.
template <int MODE>
__global__ __launch_bounds__(256) void gemm_bt(
    const u16* __restrict__ Abase, const u16* __restrict__ Bbase,
    long saB, long sbB,
    const float* __restrict__ bias, const float* __restrict__ xres,
    const float* __restrict__ gammap,
    u16* __restrict__ oq, u16* __restrict__ ok, u16* __restrict__ ov,
    float* __restrict__ of) {
  __shared__ __align__(16) u16 lsA[128 * 32];
  __shared__ __align__(16) u16 lsB[128 * 32];
  int b = blockIdx.z;
  const u16* Ag = Abase + (size_t)b * saB;
  const u16* Bg = Bbase + (size_t)b * sbB;
  int m0 = blockIdx.y * 128, n0 = blockIdx.x * 128;
  int tid = threadIdx.x;
  int w = tid >> 6, l = tid & 63;
  int wr = w >> 1, wc = w & 1;
  int lq = l >> 4, lr = l & 15;
  int rowA = w * 32 + (l >> 2);
  int k8 = (l & 3) * 8;
  f32x4 acc[4][4] = {};
  for (int kk = 0; kk < 16; ++kk) {
    int ko = kk * 32;
    __builtin_amdgcn_global_load_lds(
        AS1C(Ag + (size_t)(m0 + rowA) * 512 + ko + k8),
        AS3(&lsA[rowA * 32 + k8]), 16, 0, 0);
    __builtin_amdgcn_global_load_lds(
        AS1C(Ag + (size_t)(m0 + rowA + 16) * 512 + ko + k8),
        AS3(&lsA[(rowA + 16) * 32 + k8]), 16, 0, 0);
    __builtin_amdgcn_global_load_lds(
        AS1C(Bg + (size_t)(n0 + rowA) * 512 + ko + k8),
        AS3(&lsB[rowA * 32 + k8]), 16, 0, 0);
    __builtin_amdgcn_global_load_lds(
        AS1C(Bg + (size_t)(n0 + rowA + 16) * 512 + ko + k8),
        AS3(&lsB[(rowA + 16) * 32 + k8]), 16, 0, 0);
    __syncthreads();
    short8 af[4], bfr[4];
#pragma unroll
    for (int m = 0; m < 4; ++m)
      af[m] = *(const short8*)&lsA[(wr * 64 + m * 16 + lr) * 32 + lq * 8];
#pragma unroll
    for (int j = 0; j < 4; ++j)
      bfr[j] = *(const short8*)&lsB[(wc * 64 + j * 16 + lr) * 32 + lq * 8];
#pragma unroll
    for (int m = 0; m < 4; ++m)
#pragma unroll
      for (int j = 0; j < 4; ++j)
        acc[m][j] = __builtin_amdgcn_mfma_f32_16x16x32_bf16(af[m], bfr[j],
                                                            acc[m][j], 0, 0, 0);
    __syncthreads();
  }
  float g = (MODE == 2) ? gammap[0] : 0.f;
#pragma unroll
  for (int m = 0; m < 4; ++m)
#pragma unroll
    for (int j = 0; j < 4; ++j)
#pragma unroll
      for (int e = 0; e < 4; ++e) {
        int row = m0 + wr * 64 + m * 16 + lq * 4 + e;
        int col = n0 + wc * 64 + j * 16 + lr;
        float v = acc[m][j][e];
        if (MODE == 0) {
          int o = col, n = row;
          v += bias[o];
          int oo = (o < 512) ? o : o - 512;
          int hh = oo >> 6, cc = oo & 63;
          u16* dst = (o < 512) ? oq : ok;
          dst[((size_t)(b * 8 + hh) * 1024 + n) * 64 + cc] = to_bf16(v);
        } else if (MODE == 1) {
          int o = row, n = col;
          v += bias[o];  // bias pre-offset by +1024 on host side
          int hh = o >> 6, cc = o & 63;
          ov[((size_t)(b * 8 + hh) * 64 + cc) * 1024 + n] = to_bf16(v);
        } else {
          int o = row, n = col;
          v += bias[o];
          size_t idx = ((size_t)b * 512 + o) * 1024 + n;
          of[idx] = g * v + xres[idx];
        }
      }
}

// ---------------------------------------------------------------------------
// Flash attention, direct-load family, 64 q-rows/wave (R10 WIN config).
// ONE structural change vs R10: vf is A/B double-buffered (loop unrolled x2,
// static names), so PV(t)'s V-operand was loaded 2 iterations earlier and the
// refill targets V(t+2). kf stays single-buffered (R10 distances). Statement
// order within each iteration is exactly R10's: a) exp/pack, b) pf+lsum+PV,
// c) QKT(t+1), d) refills. Per-element arithmetic identical (0.03125 family).
#define CS 0.18033688f   // (1/sqrt(64)) * log2(e)
#define MCC 2.8853901f   // 16 * CS

__global__ __launch_bounds__(256, 2) void attn_fused(const u16* __restrict__ Qb,
                                                     const u16* __restrict__ Kb,
                                                     const u16* __restrict__ Vb,
                                                     u16* __restrict__ attnT) {
  __shared__ __align__(16) u16 Plds[4][4096];  // 8KB per wave, XOR-swizzled
  int L = blockIdx.x;  // 0..511
  // XCD-bijective swizzle: the 4 n-blocks of a bh land on one XCD (L2 reuse)
  int bh = (L & 7) | ((L >> 5) << 3);
  int nb = (L >> 3) & 3;
  int b = bh >> 3, h = bh & 7;
  int tid = threadIdx.x, w = tid >> 6, lane = tid & 63;
  int g = lane >> 4, lr = lane & 15;
  char* Pb = (char*)(&Plds[w][0]);
  const u16* Qh = Qb + (size_t)bh * 65536;
  const u16* Kh = Kb + (size_t)bh * 65536;
  const u16* Vh = Vb + (size_t)bh * 65536;
  int n_base = nb * 256 + w * 64;
  int sz = (lr & 7) << 4;  // XOR swizzle for this lane's P rows

  const short8 onesf = {0x3F80, 0x3F80, 0x3F80, 0x3F80,
                        0x3F80, 0x3F80, 0x3F80, 0x3F80};  // bf16 1.0 x8

  short8 qf[4][2];
#pragma unroll
  for (int r = 0; r < 4; ++r)
#pragma unroll
    for (int ks = 0; ks < 2; ++ks)
      qf[r][ks] = *(const short8*)&Qh[(size_t)(n_base + r * 16 + lr) * 64 +
                                      ks * 32 + g * 8];

  f32x4 O[4][4] = {};
  f32x4 lacc[4] = {};

  // ---- prologue: K(0), S(0) = QKT(0), kf <- K(1), vfA <- V(0), vfB <- V(1)
  short8 kf[4][2];
#pragma unroll
  for (int j = 0; j < 4; ++j)
#pragma unroll
    for (int ks = 0; ks < 2; ++ks)
      kf[j][ks] =
          *(const short8*)&Kh[(size_t)(j * 16 + lr) * 64 + ks * 32 + g * 8];
  f32x4 S[4][4];
#pragma unroll
  for (int j = 0; j < 4; ++j)
#pragma unroll
    for (int r = 0; r < 4; ++r) {
      f32x4 z = {};
      z = __builtin_amdgcn_mfma_f32_16x16x32_bf16(kf[j][0], qf[r][0], z, 0, 0, 0);
      z = __builtin_amdgcn_mfma_f32_16x16x32_bf16(kf[j][1], qf[r][1], z, 0, 0, 0);
      S[j][r] = z;
    }
#pragma unroll
  for (int j = 0; j < 4; ++j)
#pragma unroll
    for (int ks = 0; ks < 2; ++ks)
      kf[j][ks] = *(const short8*)&Kh[(size_t)(64 + j * 16 + lr) * 64 +
                                      ks * 32 + g * 8];
  short8 vfA[4][2], vfB[4][2];
#pragma unroll
  for (int jc = 0; jc < 4; ++jc)
#pragma unroll
    for (int ks = 0; ks < 2; ++ks) {
      vfA[jc][ks] =
          *(const short8*)&Vh[(size_t)(jc * 16 + lr) * 1024 + ks * 32 + g * 8];
      vfB[jc][ks] = *(const short8*)&Vh[(size_t)(jc * 16 + lr) * 1024 + 64 +
                                        ks * 32 + g * 8];
    }

  for (int t = 0; t < 16; t += 2) {
    // =============== even sub-iteration: kb = t, V from vfA ===============
    {
      const int kb = t;
      // ---- a) exp/pack S(kb) -> P LDS
#pragma unroll
      for (int r = 0; r < 4; ++r) {
        int rowoff = (r * 16 + lr) * 128;
#pragma unroll
        for (int j = 0; j < 4; ++j) {
          float p0 = __builtin_amdgcn_exp2f(__builtin_fmaf(S[j][r][0], CS, -MCC));
          float p1 = __builtin_amdgcn_exp2f(__builtin_fmaf(S[j][r][1], CS, -MCC));
          float p2 = __builtin_amdgcn_exp2f(__builtin_fmaf(S[j][r][2], CS, -MCC));
          float p3 = __builtin_amdgcn_exp2f(__builtin_fmaf(S[j][r][3], CS, -MCC));
          unsigned w0, w1;
          asm("v_cvt_pk_bf16_f32 %0, %1, %2" : "=v"(w0) : "v"(p0), "v"(p1));
          asm("v_cvt_pk_bf16_f32 %0, %1, %2" : "=v"(w1) : "v"(p2), "v"(p3));
          *(uint2v*)(Pb + rowoff + ((j * 32 + g * 8) ^ sz)) = (uint2v){w0, w1};
        }
      }
      // ---- b) P fragments + lsum + PV (vfA = V(kb))
      short8 pf[4][2];
#pragma unroll
      for (int r = 0; r < 4; ++r) {
        int rowoff = (r * 16 + lr) * 128;
        pf[r][0] = *(const short8*)(Pb + rowoff + ((g * 16) ^ sz));
        pf[r][1] = *(const short8*)(Pb + rowoff + ((64 + g * 16) ^ sz));
        lacc[r] = __builtin_amdgcn_mfma_f32_16x16x32_bf16(pf[r][0], onesf,
                                                          lacc[r], 0, 0, 0);
        lacc[r] = __builtin_amdgcn_mfma_f32_16x16x32_bf16(pf[r][1], onesf,
                                                          lacc[r], 0, 0, 0);
      }
#pragma unroll
      for (int jc = 0; jc < 4; ++jc)
#pragma unroll
        for (int r = 0; r < 4; ++r) {
          O[r][jc] = __builtin_amdgcn_mfma_f32_16x16x32_bf16(
              pf[r][0], vfA[jc][0], O[r][jc], 0, 0, 0);
          O[r][jc] = __builtin_amdgcn_mfma_f32_16x16x32_bf16(
              pf[r][1], vfA[jc][1], O[r][jc], 0, 0, 0);
        }
      // ---- c) S = QKT(kb+1)  (kf = K(kb+1))
#pragma unroll
      for (int j = 0; j < 4; ++j)
#pragma unroll
        for (int r = 0; r < 4; ++r) {
          f32x4 z = {};
          z = __builtin_amdgcn_mfma_f32_16x16x32_bf16(kf[j][0], qf[r][0], z, 0, 0, 0);
          z = __builtin_amdgcn_mfma_f32_16x16x32_bf16(kf[j][1], qf[r][1], z, 0, 0, 0);
          S[j][r] = z;
        }
      // ---- d) refills: vfA <- V(kb+2), kf <- K(kb+2)
      {
        int mmv = ((kb + 2) & 15) * 64;
#pragma unroll
        for (int jc = 0; jc < 4; ++jc)
#pragma unroll
          for (int ks = 0; ks < 2; ++ks)
            vfA[jc][ks] = *(const short8*)&Vh[(size_t)(jc * 16 + lr) * 1024 +
                                              mmv + ks * 32 + g * 8];
        int mmk = ((kb + 2) & 15) * 64;
#pragma unroll
        for (int j = 0; j < 4; ++j)
#pragma unroll
          for (int ks = 0; ks < 2; ++ks)
            kf[j][ks] = *(const short8*)&Kh[(size_t)(mmk + j * 16 + lr) * 64 +
                                            ks * 32 + g * 8];
      }
    }
    // =============== odd sub-iteration: kb = t+1, V from vfB ===============
    {
      const int kb = t + 1;
      // ---- a) exp/pack S(kb) -> P LDS
#pragma unroll
      for (int r = 0; r < 4; ++r) {
        int rowoff = (r * 16 + lr) * 128;
#pragma unroll
        for (int j = 0; j < 4; ++j) {
          float p0 = __builtin_amdgcn_exp2f(__builtin_fmaf(S[j][r][0], CS, -MCC));
          float p1 = __builtin_amdgcn_exp2f(__builtin_fmaf(S[j][r][1], CS, -MCC));
          float p2 = __builtin_amdgcn_exp2f(__builtin_fmaf(S[j][r][2], CS, -MCC));
          float p3 = __builtin_amdgcn_exp2f(__builtin_fmaf(S[j][r][3], CS, -MCC));
          unsigned w0, w1;
          asm("v_cvt_pk_bf16_f32 %0, %1, %2" : "=v"(w0) : "v"(p0), "v"(p1));
          asm("v_cvt_pk_bf16_f32 %0, %1, %2" : "=v"(w1) : "v"(p2), "v"(p3));
          *(uint2v*)(Pb + rowoff + ((j * 32 + g * 8) ^ sz)) = (uint2v){w0, w1};
        }
      }
      // ---- b) P fragments + lsum + PV (vfB = V(kb))
      short8 pf[4][2];
#pragma unroll
      for (int r = 0; r < 4; ++r) {
        int rowoff = (r * 16 + lr) * 128;
        pf[r][0] = *(const short8*)(Pb + rowoff + ((g * 16) ^ sz));
        pf[r][1] = *(const short8*)(Pb + rowoff + ((64 + g * 16) ^ sz));
        lacc[r] = __builtin_amdgcn_mfma_f32_16x16x32_bf16(pf[r][0], onesf,
                                                          lacc[r], 0, 0, 0);
        lacc[r] = __builtin_amdgcn_mfma_f32_16x16x32_bf16(pf[r][1], onesf,
                                                          lacc[r], 0, 0, 0);
      }
#pragma unroll
      for (int jc = 0; jc < 4; ++jc)
#pragma unroll
        for (int r = 0; r < 4; ++r) {
          O[r][jc] = __builtin_amdgcn_mfma_f32_16x16x32_bf16(
              pf[r][0], vfB[jc][0], O[r][jc], 0, 0, 0);
          O[r][jc] = __builtin_amdgcn_mfma_f32_16x16x32_bf16(
              pf[r][1], vfB[jc][1], O[r][jc], 0, 0, 0);
        }
      // ---- c) S = QKT(kb+1)  (kf = K(kb+1))
#pragma unroll
      for (int j = 0; j < 4; ++j)
#pragma unroll
        for (int r = 0; r < 4; ++r) {
          f32x4 z = {};
          z = __builtin_amdgcn_mfma_f32_16x16x32_bf16(kf[j][0], qf[r][0], z, 0, 0, 0);
          z = __builtin_amdgcn_mfma_f32_16x16x32_bf16(kf[j][1], qf[r][1], z, 0, 0, 0);
          S[j][r] = z;
        }
      // ---- d) refills: vfB <- V(kb+2), kf <- K(kb+2)
      {
        int mmv = ((kb + 2) & 15) * 64;
#pragma unroll
        for (int jc = 0; jc < 4; ++jc)
#pragma unroll
          for (int ks = 0; ks < 2; ++ks)
            vfB[jc][ks] = *(const short8*)&Vh[(size_t)(jc * 16 + lr) * 1024 +
                                              mmv + ks * 32 + g * 8];
        int mmk = ((kb + 2) & 15) * 64;
#pragma unroll
        for (int j = 0; j < 4; ++j)
#pragma unroll
          for (int ks = 0; ks < 2; ++ks)
            kf[j][ks] = *(const short8*)&Kh[(size_t)(mmk + j * 16 + lr) * 64 +
                                            ks * 32 + g * 8];
      }
    }
  }
  // ---- normalize + store attnT[b][n][h*64 + c]; lacc is in O's row layout
#pragma unroll
  for (int r = 0; r < 4; ++r)
#pragma unroll
    for (int e = 0; e < 4; ++e) {
      float rl = 1.0f / lacc[r][e];
      int n = n_base + r * 16 + g * 4 + e;
#pragma unroll
      for (int jc = 0; jc < 4; ++jc)
        attnT[((size_t)b * 1024 + n) * 512 + h * 64 + jc * 16 + lr] =
            to_bf16(O[r][jc][e] * rl);
    }
}

// ---------------------------------------------------------------------------
extern "C" void kernel_launch(void* const* d_in, const int* in_sizes, int n_in,
                              void* d_out, int out_size, void* d_ws,
                              size_t ws_size, hipStream_t stream) {
  const float* x      = (const float*)d_in[0];  // (16,512,32,32)
  const float* qkv_w  = (const float*)d_in[1];  // (1536,512)
  const float* qkv_b  = (const float*)d_in[2];  // (1536,)
  const float* out_w  = (const float*)d_in[3];  // (512,512)
  const float* out_b  = (const float*)d_in[4];  // (512,)
  const float* gamma  = (const float*)d_in[5];  // (1,)
  float* out = (float*)d_out;

  u16* xT  = (u16*)d_ws;          // [16][1024][512]
  u16* Qb  = xT + 8388608;        // [128][1024][64]
  u16* Kbf = Qb + 8388608;        // [128][1024][64]
  u16* Vbf = Kbf + 8388608;       // [128][64][1024]
  u16* aT  = Vbf + 8388608;       // [16][1024][512]
  u16* wq  = aT + 8388608;        // qkv_w bf16 (1536*512)
  u16* wo  = wq + 786432;         // out_w bf16 (512*512)

  // 1) convert / transpose inputs to bf16 (vectorized; values bit-identical)
  xpose_cvt<<<dim3(32, 8, 16), 256, 0, stream>>>(x, xT);
  cvt_both<<<1024, 256, 0, stream>>>(qkv_w, out_w, wq, wo);

  // 2) QKV projection. Q,K via transposed orientation (rows=n, cols=o<1024)
  gemm_bt<0><<<dim3(8, 8, 16), 256, 0, stream>>>(
      xT, wq, (long)524288, (long)0, qkv_b, nullptr, nullptr, Qb, Kbf, nullptr,
      nullptr);
  // 3) V via normal orientation (rows=o' in [0,512), cols=n)
  gemm_bt<1><<<dim3(8, 4, 16), 256, 0, stream>>>(
      wq + 524288, xT, (long)0, (long)524288, qkv_b + 1024, nullptr, nullptr,
      nullptr, nullptr, Vbf, nullptr);

  // 4) fused flash attention -> attnT[b][n][512]  (vf A/B, 2-deep V prefetch)
  attn_fused<<<512, 256, 0, stream>>>(Qb, Kbf, Vbf, aT);

  // 5) output projection + bias + gamma*out + x  -> fp32 d_out
  gemm_bt<2><<<dim3(8, 4, 16), 256, 0, stream>>>(
      wo, aT, (long)0, (long)524288, out_b, x, gamma, nullptr, nullptr, nullptr,
      out);
}

// Round 13
// 153.315 us; speedup vs baseline: 1.1250x; 1.1250x over previous
//
#include <hip/hip_runtime.h>
#include <stdint.h>

typedef unsigned short u16;
typedef __attribute__((ext_vector_type(8))) short short8;
typedef __attribute__((ext_vector_type(4))) short short4v;
typedef __attribute__((ext_vector_type(4))) float f32x4;
typedef __attribute__((ext_vector_type(2))) unsigned uint2v;

#define AS1C(p) ((const __attribute__((address_space(1))) void*)(p))
#define AS3(p)  ((__attribute__((address_space(3))) void*)(p))

__device__ __forceinline__ u16 to_bf16(float f) {
  unsigned u = __builtin_bit_cast(unsigned, f);
  u += 0x7FFFu + ((u >> 16) & 1u);
  return (u16)(u >> 16);
}

// ---------------------------------------------------------------------------
// x[b][c][n] fp32 -> xT[b][n][c] bf16. Tile 64c x 32n, short4 stores.
__global__ __launch_bounds__(256) void xpose_cvt(const float* __restrict__ x,
                                                 u16* __restrict__ xT) {
  __shared__ float ls[64][34];
  int b = blockIdx.z;
  int n0 = blockIdx.x * 32, c0 = blockIdx.y * 64;
  int t = threadIdx.x;
  const float* xp = x + (size_t)b * 524288;
  int nn = t & 31, ccb = (t >> 5) * 8;
#pragma unroll
  for (int i = 0; i < 8; ++i)
    ls[ccb + i][nn] = xp[(size_t)(c0 + ccb + i) * 1024 + n0 + nn];
  __syncthreads();
  u16* op = xT + (size_t)b * 524288 + (size_t)n0 * 512 + c0;
  int nn2 = t >> 3, cb = (t & 7) * 4;
#pragma unroll
  for (int pass = 0; pass < 2; ++pass) {
    int c = cb + pass * 32;
    short4v v;
#pragma unroll
    for (int i = 0; i < 4; ++i) v[i] = (short)to_bf16(ls[c + i][nn2]);
    *(short4v*)&op[(size_t)nn2 * 512 + c] = v;
  }
}

__global__ __launch_bounds__(256) void cvt_bf16_v4(const float* __restrict__ s,
                                                   u16* __restrict__ d, int n4) {
  int i = blockIdx.x * 256 + threadIdx.x;
  if (i < n4) {
    f32x4 v = *(const f32x4*)&s[i * 4];
    short4v o;
#pragma unroll
    for (int j = 0; j < 4; ++j) o[j] = (short)to_bf16(v[j]);
    *(short4v*)&d[i * 4] = o;
  }
}

// ---------------------------------------------------------------------------
// Generic 128x128-tile bf16 GEMM, K=512, BK=32 (m97 structure; linear
// K/V output layouts).
template <int MODE>
__global__ __launch_bounds__(256) void gemm_bt(
    const u16* __restrict__ Abase, const u16* __restrict__ Bbase,
    long saB, long sbB,
    const float* __restrict__ bias, const float* __restrict__ xres,
    const float* __restrict__ gammap,
    u16* __restrict__ oq, u16* __restrict__ ok, u16* __restrict__ ov,
    float* __restrict__ of) {
  __shared__ __align__(16) u16 lsA[128 * 32];
  __shared__ __align__(16) u16 lsB[128 * 32];
  int b = blockIdx.z;
  const u16* Ag = Abase + (size_t)b * saB;
  const u16* Bg = Bbase + (size_t)b * sbB;
  int m0 = blockIdx.y * 128, n0 = blockIdx.x * 128;
  int tid = threadIdx.x;
  int w = tid >> 6, l = tid & 63;
  int wr = w >> 1, wc = w & 1;
  int lq = l >> 4, lr = l & 15;
  int rowA = w * 32 + (l >> 2);
  int k8 = (l & 3) * 8;
  f32x4 acc[4][4] = {};
  for (int kk = 0; kk < 16; ++kk) {
    int ko = kk * 32;
    __builtin_amdgcn_global_load_lds(
        AS1C(Ag + (size_t)(m0 + rowA) * 512 + ko + k8),
        AS3(&lsA[rowA * 32 + k8]), 16, 0, 0);
    __builtin_amdgcn_global_load_lds(
        AS1C(Ag + (size_t)(m0 + rowA + 16) * 512 + ko + k8),
        AS3(&lsA[(rowA + 16) * 32 + k8]), 16, 0, 0);
    __builtin_amdgcn_global_load_lds(
        AS1C(Bg + (size_t)(n0 + rowA) * 512 + ko + k8),
        AS3(&lsB[rowA * 32 + k8]), 16, 0, 0);
    __builtin_amdgcn_global_load_lds(
        AS1C(Bg + (size_t)(n0 + rowA + 16) * 512 + ko + k8),
        AS3(&lsB[(rowA + 16) * 32 + k8]), 16, 0, 0);
    __syncthreads();
    short8 af[4], bfr[4];
#pragma unroll
    for (int m = 0; m < 4; ++m)
      af[m] = *(const short8*)&lsA[(wr * 64 + m * 16 + lr) * 32 + lq * 8];
#pragma unroll
    for (int j = 0; j < 4; ++j)
      bfr[j] = *(const short8*)&lsB[(wc * 64 + j * 16 + lr) * 32 + lq * 8];
#pragma unroll
    for (int m = 0; m < 4; ++m)
#pragma unroll
      for (int j = 0; j < 4; ++j)
        acc[m][j] = __builtin_amdgcn_mfma_f32_16x16x32_bf16(af[m], bfr[j],
                                                            acc[m][j], 0, 0, 0);
    __syncthreads();
  }
  float g = (MODE == 2) ? gammap[0] : 0.f;
#pragma unroll
  for (int m = 0; m < 4; ++m)
#pragma unroll
    for (int j = 0; j < 4; ++j)
#pragma unroll
      for (int e = 0; e < 4; ++e) {
        int row = m0 + wr * 64 + m * 16 + lq * 4 + e;
        int col = n0 + wc * 64 + j * 16 + lr;
        float v = acc[m][j][e];
        if (MODE == 0) {
          int o = col, n = row;
          v += bias[o];
          int oo = (o < 512) ? o : o - 512;
          int hh = oo >> 6, cc = oo & 63;
          u16* dst = (o < 512) ? oq : ok;
          dst[((size_t)(b * 8 + hh) * 1024 + n) * 64 + cc] = to_bf16(v);
        } else if (MODE == 1) {
          int o = row, n = col;
          v += bias[o];  // bias pre-offset by +1024 on host side
          int hh = o >> 6, cc = o & 63;
          ov[((size_t)(b * 8 + hh) * 64 + cc) * 1024 + n] = to_bf16(v);
        } else {
          int o = row, n = col;
          v += bias[o];
          size_t idx = ((size_t)b * 512 + o) * 1024 + n;
          of[idx] = g * v + xres[idx];
        }
      }
}

// ---------------------------------------------------------------------------
// Flash attention, direct-load family, 64 q-rows/wave (the R10 WIN config,
// restored verbatim: absmax exactly 0.03125, attn ~77.5 us). No barriers,
// no setprio, no LDS K/V staging; P buffer wave-private; single-buffered
// vf/kf register prefetch (V at ~1-phase distance, K at ~2-phase distance).
#define CS 0.18033688f   // (1/sqrt(64)) * log2(e)
#define MCC 2.8853901f   // 16 * CS

__global__ __launch_bounds__(256, 2) void attn_fused(const u16* __restrict__ Qb,
                                                     const u16* __restrict__ Kb,
                                                     const u16* __restrict__ Vb,
                                                     u16* __restrict__ attnT) {
  __shared__ __align__(16) u16 Plds[4][4096];  // 8KB per wave, XOR-swizzled
  int L = blockIdx.x;  // 0..511
  // XCD-bijective swizzle: the 4 n-blocks of a bh land on one XCD (L2 reuse)
  int bh = (L & 7) | ((L >> 5) << 3);
  int nb = (L >> 3) & 3;
  int b = bh >> 3, h = bh & 7;
  int tid = threadIdx.x, w = tid >> 6, lane = tid & 63;
  int g = lane >> 4, lr = lane & 15;
  char* Pb = (char*)(&Plds[w][0]);
  const u16* Qh = Qb + (size_t)bh * 65536;
  const u16* Kh = Kb + (size_t)bh * 65536;
  const u16* Vh = Vb + (size_t)bh * 65536;
  int n_base = nb * 256 + w * 64;
  int sz = (lr & 7) << 4;  // XOR swizzle for this lane's P rows

  const short8 onesf = {0x3F80, 0x3F80, 0x3F80, 0x3F80,
                        0x3F80, 0x3F80, 0x3F80, 0x3F80};  // bf16 1.0 x8

  short8 qf[4][2];
#pragma unroll
  for (int r = 0; r < 4; ++r)
#pragma unroll
    for (int ks = 0; ks < 2; ++ks)
      qf[r][ks] = *(const short8*)&Qh[(size_t)(n_base + r * 16 + lr) * 64 +
                                      ks * 32 + g * 8];

  f32x4 O[4][4] = {};
  f32x4 lacc[4] = {};

  // ---- prologue: K(0), S(0) = QKT(0), K(1), V(0)
  short8 kf[4][2];
#pragma unroll
  for (int j = 0; j < 4; ++j)
#pragma unroll
    for (int ks = 0; ks < 2; ++ks)
      kf[j][ks] =
          *(const short8*)&Kh[(size_t)(j * 16 + lr) * 64 + ks * 32 + g * 8];
  f32x4 S[4][4];
#pragma unroll
  for (int j = 0; j < 4; ++j)
#pragma unroll
    for (int r = 0; r < 4; ++r) {
      f32x4 z = {};
      z = __builtin_amdgcn_mfma_f32_16x16x32_bf16(kf[j][0], qf[r][0], z, 0, 0, 0);
      z = __builtin_amdgcn_mfma_f32_16x16x32_bf16(kf[j][1], qf[r][1], z, 0, 0, 0);
      S[j][r] = z;
    }
#pragma unroll
  for (int j = 0; j < 4; ++j)
#pragma unroll
    for (int ks = 0; ks < 2; ++ks)
      kf[j][ks] = *(const short8*)&Kh[(size_t)(64 + j * 16 + lr) * 64 +
                                      ks * 32 + g * 8];
  short8 vf[4][2];
#pragma unroll
  for (int jc = 0; jc < 4; ++jc)
#pragma unroll
    for (int ks = 0; ks < 2; ++ks)
      vf[jc][ks] =
          *(const short8*)&Vh[(size_t)(jc * 16 + lr) * 1024 + ks * 32 + g * 8];

  for (int kb = 0; kb < 16; ++kb) {
    // ---- a) exp/pack S(kb) -> P LDS (frees S for this iteration)
#pragma unroll
    for (int r = 0; r < 4; ++r) {
      int rowoff = (r * 16 + lr) * 128;
#pragma unroll
      for (int j = 0; j < 4; ++j) {
        float p0 = __builtin_amdgcn_exp2f(__builtin_fmaf(S[j][r][0], CS, -MCC));
        float p1 = __builtin_amdgcn_exp2f(__builtin_fmaf(S[j][r][1], CS, -MCC));
        float p2 = __builtin_amdgcn_exp2f(__builtin_fmaf(S[j][r][2], CS, -MCC));
        float p3 = __builtin_amdgcn_exp2f(__builtin_fmaf(S[j][r][3], CS, -MCC));
        unsigned w0, w1;
        asm("v_cvt_pk_bf16_f32 %0, %1, %2" : "=v"(w0) : "v"(p0), "v"(p1));
        asm("v_cvt_pk_bf16_f32 %0, %1, %2" : "=v"(w1) : "v"(p2), "v"(p3));
        *(uint2v*)(Pb + rowoff + ((j * 32 + g * 8) ^ sz)) = (uint2v){w0, w1};
      }
    }
    // ---- b) read P(kb) fragments + lsum + PV (vf = V(kb))
    short8 pf[4][2];
#pragma unroll
    for (int r = 0; r < 4; ++r) {
      int rowoff = (r * 16 + lr) * 128;
      pf[r][0] = *(const short8*)(Pb + rowoff + ((g * 16) ^ sz));
      pf[r][1] = *(const short8*)(Pb + rowoff + ((64 + g * 16) ^ sz));
      lacc[r] = __builtin_amdgcn_mfma_f32_16x16x32_bf16(pf[r][0], onesf,
                                                        lacc[r], 0, 0, 0);
      lacc[r] = __builtin_amdgcn_mfma_f32_16x16x32_bf16(pf[r][1], onesf,
                                                        lacc[r], 0, 0, 0);
    }
#pragma unroll
    for (int jc = 0; jc < 4; ++jc)
#pragma unroll
      for (int r = 0; r < 4; ++r) {
        O[r][jc] = __builtin_amdgcn_mfma_f32_16x16x32_bf16(pf[r][0], vf[jc][0],
                                                           O[r][jc], 0, 0, 0);
        O[r][jc] = __builtin_amdgcn_mfma_f32_16x16x32_bf16(pf[r][1], vf[jc][1],
                                                           O[r][jc], 0, 0, 0);
      }
    // ---- c) S = QKT(kb+1)  (kf = K(kb+1))
#pragma unroll
    for (int j = 0; j < 4; ++j)
#pragma unroll
      for (int r = 0; r < 4; ++r) {
        f32x4 z = {};
        z = __builtin_amdgcn_mfma_f32_16x16x32_bf16(kf[j][0], qf[r][0], z, 0, 0, 0);
        z = __builtin_amdgcn_mfma_f32_16x16x32_bf16(kf[j][1], qf[r][1], z, 0, 0, 0);
        S[j][r] = z;
      }
    // ---- d) vf <- V(kb+1), kf <- K(kb+2)  (wrap; tail loads harmless)
    {
      int mm1 = ((kb + 1) & 15) * 64;
#pragma unroll
      for (int jc = 0; jc < 4; ++jc)
#pragma unroll
        for (int ks = 0; ks < 2; ++ks)
          vf[jc][ks] = *(const short8*)&Vh[(size_t)(jc * 16 + lr) * 1024 + mm1 +
                                           ks * 32 + g * 8];
      int mm2 = ((kb + 2) & 15) * 64;
#pragma unroll
      for (int j = 0; j < 4; ++j)
#pragma unroll
        for (int ks = 0; ks < 2; ++ks)
          kf[j][ks] = *(const short8*)&Kh[(size_t)(mm2 + j * 16 + lr) * 64 +
                                          ks * 32 + g * 8];
    }
  }
  // ---- normalize + store attnT[b][n][h*64 + c]; lacc is in O's row layout
#pragma unroll
  for (int r = 0; r < 4; ++r)
#pragma unroll
    for (int e = 0; e < 4; ++e) {
      float rl = 1.0f / lacc[r][e];
      int n = n_base + r * 16 + g * 4 + e;
#pragma unroll
      for (int jc = 0; jc < 4; ++jc)
        attnT[((size_t)b * 1024 + n) * 512 + h * 64 + jc * 16 + lr] =
            to_bf16(O[r][jc][e] * rl);
    }
}

// ---------------------------------------------------------------------------
extern "C" void kernel_launch(void* const* d_in, const int* in_sizes, int n_in,
                              void* d_out, int out_size, void* d_ws,
                              size_t ws_size, hipStream_t stream) {
  const float* x      = (const float*)d_in[0];  // (16,512,32,32)
  const float* qkv_w  = (const float*)d_in[1];  // (1536,512)
  const float* qkv_b  = (const float*)d_in[2];  // (1536,)
  const float* out_w  = (const float*)d_in[3];  // (512,512)
  const float* out_b  = (const float*)d_in[4];  // (512,)
  const float* gamma  = (const float*)d_in[5];  // (1,)
  float* out = (float*)d_out;

  u16* xT  = (u16*)d_ws;          // [16][1024][512]
  u16* Qb  = xT + 8388608;        // [128][1024][64]
  u16* Kbf = Qb + 8388608;        // [128][1024][64]
  u16* Vbf = Kbf + 8388608;       // [128][64][1024]
  u16* aT  = Vbf + 8388608;       // [16][1024][512]
  u16* wq  = aT + 8388608;        // qkv_w bf16 (1536*512)
  u16* wo  = wq + 786432;         // out_w bf16 (512*512)

  // 1) convert / transpose inputs to bf16 (vectorized; values bit-identical)
  xpose_cvt<<<dim3(32, 8, 16), 256, 0, stream>>>(x, xT);
  cvt_bf16_v4<<<768, 256, 0, stream>>>(qkv_w, wq, 196608);
  cvt_bf16_v4<<<256, 256, 0, stream>>>(out_w, wo, 65536);

  // 2) QKV projection. Q,K via transposed orientation (rows=n, cols=o<1024)
  gemm_bt<0><<<dim3(8, 8, 16), 256, 0, stream>>>(
      xT, wq, (long)524288, (long)0, qkv_b, nullptr, nullptr, Qb, Kbf, nullptr,
      nullptr);
  // 3) V via normal orientation (rows=o' in [0,512), cols=n)
  gemm_bt<1><<<dim3(8, 4, 16), 256, 0, stream>>>(
      wq + 524288, xT, (long)0, (long)524288, qkv_b + 1024, nullptr, nullptr,
      nullptr, nullptr, Vbf, nullptr);

  // 4) fused flash attention -> attnT[b][n][512]  (64 q-rows per wave)
  attn_fused<<<512, 256, 0, stream>>>(Qb, Kbf, Vbf, aT);

  // 5) output projection + bias + gamma*out + x  -> fp32 d_out
  gemm_bt<2><<<dim3(8, 4, 16), 256, 0, stream>>>(
      wo, aT, (long)0, (long)524288, out_b, x, gamma, nullptr, nullptr, nullptr,
      out);
}